// Round 7
// baseline (48.397 us; speedup 1.0000x reference)
//
#include <hip/hip_runtime.h>

#define KDIM 256
#define DWIN 20
#define NOBS 8192
#define TAU  20
#define TROWS (NOBS - TAU)          // 8172
#define KTOT  (DWIN * KDIM)         // 5120
#define KSTEPS (KTOT / 32)          // 160
#define QSTEPS (KSTEPS / 4)         // 40 per K-quarter wave

#define BM 128
#define NBLK_M ((TROWS + BM - 1) / BM)   // 64
#define NBLK   (NBLK_M * 4)              // 256  -> 1 block/CU, 512 thr

#define AROWS 147                    // 128 + DWIN - 1
#define APAD  264                    // 528B row stride (balanced banks)

// dynamic LDS: A panel (77,616B); C-exchange (64KB) reuses it after the loop
#define PC_SLOT   1024               // f32x4 units per 16KB slot
#define SRED_OFF  77632
#define DYN_TOTAL 77648

typedef __bf16 bf16x8 __attribute__((ext_vector_type(8)));
typedef float  f32x4  __attribute__((ext_vector_type(4)));
typedef unsigned short u16x8 __attribute__((ext_vector_type(8)));

// ws layout (bytes):
#define WS_BF    0u
#define WS_NEED  (KSTEPS * 16u * 64u * 8u * 2u + 8192u)   // Bf + slack

__device__ __forceinline__ unsigned short f2bf(float f) {
    unsigned int u = __float_as_uint(f);
    unsigned int r = (u + 0x7fffu + ((u >> 16) & 1u)) >> 16;   // RN-even
    return (unsigned short)r;
}

// ---- prep: beta1 -> fragment-major B, COALESCED via LDS transpose ----
// Layout (verified R2-R6): Bf[((ks*16 + nt)*64 + lane)*8 + j] = bf16(B[k][n]),
//   k = ks*32 + (lane>>4)*8 + j,  n = nt*16 + (lane&15),  B[k][n] = beta1[n][k&255][k>>8]
// One block per n: load beta1[n][:] (5120 f32, coalesced) into LDS, gather out.
__global__ __launch_bounds__(256)
void prep_bfrag_kernel(const float* __restrict__ beta1,
                       unsigned short* __restrict__ Bf,
                       float* __restrict__ out)
{
    __shared__ float L[KTOT];        // 20KB
    const int n   = blockIdx.x;
    const int tid = threadIdx.x;
    if (n == 0 && tid == 0) out[0] = 0.f;   // zero loglik accumulator

    const float4* src = (const float4*)(beta1 + (size_t)n * KTOT);
#pragma unroll
    for (int i = 0; i < 5; ++i)
        ((float4*)L)[tid + i * 256] = src[tid + i * 256];
    __syncthreads();

    const int nt = n >> 4, qn = n & 15;
    for (int c = tid; c < 640; c += 256) {       // c = ks*4 + g
        const int ks = c >> 2, g = c & 3;
        const int kbase = ks * 32 + g * 8;
        u16x8 r;
#pragma unroll
        for (int j = 0; j < 8; ++j) {
            int k = kbase + j;
            r[j] = f2bf(L[(k & 255) * DWIN + (k >> 8)]);
        }
        *(u16x8*)&Bf[(((size_t)ks * 16 + nt) * 64 + g * 16 + qn) * 8] = r;
    }
}

extern __shared__ char dynlds[];

// ---- main GEMM: block 128x64 output, 8 waves = 2 M-halves x 4 K-quarters,
//      barrier-free K-loop, B global->register 4-deep ring ----
__global__ __launch_bounds__(512, 2)
void gemm_kernel(const float* __restrict__ obs,
                 const float* __restrict__ beta0,
                 const unsigned short* __restrict__ Bf,
                 float* __restrict__ out)
{
    const int tid  = threadIdx.x;
    const int lane = tid & 63;
    const int w    = tid >> 6;     // 0..7
    const int mh   = w >> 2;       // M-half (64 rows)
    const int kq   = w & 3;        // K-quarter owner
    const int g = lane >> 4;
    const int q = lane & 15;
    const int nb = blockIdx.x & 3;
    const int mb = blockIdx.x >> 2;
    const int i0 = mb * BM;

    unsigned short* ldsA = (unsigned short*)dynlds;

    // B slice: phase ks at +ks*16KB; nb quadrant +4KB*nb; t-tile +1KB*t; lane*16B
    const char* bbase = (const char*)Bf + (size_t)(4 * nb) * 1024
                      + (size_t)(QSTEPS * kq) * 16384 + (size_t)lane * 16;

#define BADDR(s) (bbase + (size_t)((s) < QSTEPS ? (s) : QSTEPS - 1) * 16384)
#define LOADB(dst, s)                                                            \
    {                                                                            \
        const char* _p = BADDR(s);                                               \
        _Pragma("unroll")                                                        \
        for (int t = 0; t < 4; ++t)                                              \
            dst[t] = *(const bf16x8*)(_p + t * 1024);                            \
    }

    bf16x8 rb0[4], rb1[4], rb2[4], rb3[4];
    LOADB(rb0, 0)
    LOADB(rb1, 1)
    LOADB(rb2, 2)

    // --- stage A panel: rows i0..i0+146 (clamped), fused fp32->bf16 ---
    for (int idx = tid; idx < AROWS * 64; idx += 512) {
        int row = idx >> 6, c4 = idx & 63;
        int grow = min(i0 + row, NOBS - 1);
        float4 v = ((const float4*)obs)[(size_t)grow * 64 + c4];
        ushort4 r;
        r.x = f2bf(v.x); r.y = f2bf(v.y); r.z = f2bf(v.z); r.w = f2bf(v.w);
        *(ushort4*)&ldsA[row * APAD + c4 * 4] = r;
    }
    __syncthreads();

    f32x4 acc[4][4];
#pragma unroll
    for (int m = 0; m < 4; ++m)
#pragma unroll
        for (int t = 0; t < 4; ++t)
            acc[m][t] = (f32x4){0.f, 0.f, 0.f, 0.f};

#define COMPUTE(s, breg)                                                         \
    {                                                                            \
        const int _ks = QSTEPS * kq + (s);                                       \
        const int _acol = ((_ks & 7) * 32 + g * 8);                              \
        const int _aro  = (_ks >> 3);                                            \
        bf16x8 _af[4];                                                           \
        _Pragma("unroll")                                                        \
        for (int m = 0; m < 4; ++m)                                              \
            _af[m] = *(const bf16x8*)&ldsA[(mh * 64 + m * 16 + q + _aro) * APAD + _acol]; \
        _Pragma("unroll")                                                        \
        for (int t = 0; t < 4; ++t)                                              \
            _Pragma("unroll")                                                    \
            for (int m = 0; m < 4; ++m)                                          \
                acc[m][t] = __builtin_amdgcn_mfma_f32_16x16x32_bf16(_af[m], (breg)[t], acc[m][t], 0, 0, 0); \
    }

#pragma unroll 1
    for (int s4 = 0; s4 < QSTEPS; s4 += 4) {
        LOADB(rb3, s4 + 3)
        COMPUTE(s4 + 0, rb0)
        LOADB(rb0, s4 + 4)
        COMPUTE(s4 + 1, rb1)
        LOADB(rb1, s4 + 5)
        COMPUTE(s4 + 2, rb2)
        LOADB(rb2, s4 + 6)
        COMPUTE(s4 + 3, rb3)
    }

    // --- pairwise K-quarter reduction through LDS (reuses A region) ---
    __syncthreads();
    f32x4* pc = (f32x4*)dynlds;      // 4 slots x 16KB = 64KB
    if (kq >= 2) {
        f32x4* dst = pc + (size_t)(mh * 2 + (kq - 2)) * PC_SLOT + lane;
#pragma unroll
        for (int m = 0; m < 4; ++m)
#pragma unroll
            for (int t = 0; t < 4; ++t)
                dst[(m * 4 + t) * 64] = acc[m][t];
    }
    __syncthreads();
    if (kq < 2) {
        const f32x4* sp = pc + (size_t)(mh * 2 + kq) * PC_SLOT + lane;
#pragma unroll
        for (int m = 0; m < 4; ++m)
#pragma unroll
            for (int t = 0; t < 4; ++t)
                acc[m][t] += sp[(m * 4 + t) * 64];
    }
    __syncthreads();
    if (kq == 1) {
        f32x4* dst = pc + (size_t)(mh * 2) * PC_SLOT + lane;
#pragma unroll
        for (int m = 0; m < 4; ++m)
#pragma unroll
            for (int t = 0; t < 4; ++t)
                dst[(m * 4 + t) * 64] = acc[m][t];
    }
    __syncthreads();

    double part = 0.0;
    if (kq == 0) {
        const f32x4* sp = pc + (size_t)(mh * 2) * PC_SLOT + lane;
#pragma unroll
        for (int m = 0; m < 4; ++m)
#pragma unroll
            for (int t = 0; t < 4; ++t)
                acc[m][t] += sp[(m * 4 + t) * 64];

        // --- fused epilogue: lam = acc + beta0, write, loglik partial ---
#pragma unroll
        for (int t = 0; t < 4; ++t) {
            const int col = nb * 64 + t * 16 + q;
            const float b0v = beta0[col];
#pragma unroll
            for (int m = 0; m < 4; ++m) {
#pragma unroll
                for (int r = 0; r < 4; ++r) {
                    const int row = i0 + mh * 64 + m * 16 + 4 * g + r;  // C/D: row=(lane>>4)*4+reg
                    if (row < TROWS) {
                        float lam = acc[m][t][r] + b0v;
                        out[1 + (size_t)row * KDIM + col] = lam;
                        float o = obs[(size_t)(row + TAU) * KDIM + col];
                        part += (double)o * (double)__logf(lam) - (double)lam;
                    }
                }
            }
        }
#pragma unroll
        for (int off = 32; off > 0; off >>= 1) part += __shfl_down(part, off, 64);
    }

    double* sred = (double*)(dynlds + SRED_OFF);
    if (kq == 0 && lane == 0) sred[mh] = part;
    __syncthreads();
    if (tid == 0) atomicAdd(out, (float)(sred[0] + sred[1]));
}

// ================= fallback fp32 path (R1, proven) =================
#define BM_OLD 16
#define NBLK_OLD ((TROWS + BM_OLD - 1) / BM_OLD)   // 511

__global__ __launch_bounds__(KDIM, 2)
void old_lam_kernel(const float* __restrict__ obs,
                    const float* __restrict__ beta0,
                    const float* __restrict__ beta1,
                    float* __restrict__ out,
                    double* __restrict__ partials)
{
    const int k  = threadIdx.x;
    const int i0 = blockIdx.x * BM_OLD;
    const int nr = min(BM_OLD, TROWS - i0);
    const int smax = nr + DWIN - 1;

    float acc[BM_OLD];
#pragma unroll
    for (int r = 0; r < BM_OLD; ++r) acc[r] = 0.f;

    const float* __restrict__ b1k = beta1 + (size_t)k * (KDIM * DWIN);

    for (int b = 0; b < KDIM; ++b) {
        float br[DWIN];
        const float4* qd = (const float4*)(b1k + b * DWIN);
#pragma unroll
        for (int v = 0; v < DWIN / 4; ++v) {
            float4 t = qd[v];
            br[4*v+0] = t.x; br[4*v+1] = t.y; br[4*v+2] = t.z; br[4*v+3] = t.w;
        }
        float wv[BM_OLD + DWIN - 1];
#pragma unroll
        for (int s = 0; s < BM_OLD + DWIN - 1; ++s)
            wv[s] = (s < smax) ? obs[(size_t)(i0 + s) * KDIM + b] : 0.f;
#pragma unroll
        for (int r = 0; r < BM_OLD; ++r)
#pragma unroll
            for (int a = 0; a < DWIN; ++a)
                acc[r] = fmaf(wv[r + a], br[a], acc[r]);
    }

    const float b0 = beta0[k];
    double part = 0.0;
    for (int r = 0; r < nr; ++r) {
        float lam = acc[r] + b0;
        out[1 + (size_t)(i0 + r) * KDIM + k] = lam;
        float o = obs[(size_t)(i0 + r + TAU) * KDIM + k];
        part += (double)(o * logf(lam) - lam);
    }

    __shared__ double sred2[KDIM];
    sred2[k] = part;
    __syncthreads();
    for (int off = KDIM / 2; off > 0; off >>= 1) {
        if (k < off) sred2[k] += sred2[k + off];
        __syncthreads();
    }
    if (k == 0) partials[blockIdx.x] = sred2[0];
}

__global__ void reduce_final_kernel(const double* __restrict__ partials,
                                    float* __restrict__ out, int n)
{
    __shared__ double sr[256];
    double v = 0.0;
    for (int i = threadIdx.x; i < n; i += 256) v += partials[i];
    sr[threadIdx.x] = v;
    __syncthreads();
    for (int off = 128; off > 0; off >>= 1) {
        if (threadIdx.x < off) sr[threadIdx.x] += sr[threadIdx.x + off];
        __syncthreads();
    }
    if (threadIdx.x == 0) out[0] = (float)sr[0];
}
// ===================================================================

extern "C" void kernel_launch(void* const* d_in, const int* in_sizes, int n_in,
                              void* d_out, int out_size, void* d_ws, size_t ws_size,
                              hipStream_t stream)
{
    const float* obs   = (const float*)d_in[0];
    const float* beta0 = (const float*)d_in[1];
    const float* beta1 = (const float*)d_in[2];
    float* out = (float*)d_out;

    if (ws_size >= (size_t)WS_NEED) {
        unsigned short* Bf = (unsigned short*)((char*)d_ws + WS_BF);

        (void)hipFuncSetAttribute(reinterpret_cast<const void*>(gemm_kernel),
                                  hipFuncAttributeMaxDynamicSharedMemorySize,
                                  DYN_TOTAL);

        hipLaunchKernelGGL(prep_bfrag_kernel, dim3(KDIM), dim3(256), 0, stream,
                           beta1, Bf, out);
        hipLaunchKernelGGL(gemm_kernel, dim3(NBLK), dim3(512), DYN_TOTAL, stream,
                           obs, beta0, Bf, out);
    } else {
        double* partials = (double*)d_ws;
        hipLaunchKernelGGL(old_lam_kernel, dim3(NBLK_OLD), dim3(KDIM), 0, stream,
                           obs, beta0, beta1, out, partials);
        hipLaunchKernelGGL(reduce_final_kernel, dim3(1), dim3(256), 0, stream,
                           partials, out, NBLK_OLD);
    }
}